// Round 12
// baseline (831.456 us; speedup 1.0000x reference)
//
#include <hip/hip_runtime.h>
#include <stdint.h>
#include <math.h>

typedef unsigned long long u64;
typedef unsigned int u32;
typedef _Float16 half8 __attribute__((ext_vector_type(8)));
typedef float f32x4 __attribute__((ext_vector_type(4)));

#define CC   512
#define HH   50
#define WW2  76
#define PP   3800      // HH*WW2
#define NB   8
#define NA   34200     // PP*9
#define PRE  6000
#define POST 300
#define NPAD 8192      // candidate buffer size per image
#define SHALF 4096     // per-block bitonic sort size (NPAD/2)
#define SCHUNK 1069    // float4-chunks per select block (8 blocks x 1069 >= 8550)

// ---------------- workspace layout (bytes) ----------------
// wh2   @ 0            65,536      (64 x 512 f16)  [head weights hi]
// wl2   @ 65,536       65,536
// whF   @ 131,072      4,718,592   (frag-major conv weights hi: [g][kk][lane][8])
// wlF   @ 4,849,664    4,718,592
// xh    @ 9,568,256    15,564,800  (4 img * 3800 * 512 f16, per-batch)
// xl    @ 25,133,056   15,564,800
// --- after conv, xh/xl dead; overlay: ---
// boxes @ 17,350,656   4,377,600
// scores@ 21,728,256   1,094,400
// sb    @ 22,822,656     192,000
// bbs   @ 23,014,656     768,000
// areas @ 23,782,656     192,000
// fh    @ 40,697,856   31,129,600
// fl    @ 71,827,456   31,129,600
// selst @ 109,581,056     16,384   (ghist 8192 | gccnt | gpref | grem | gdone | gflag)
// arr   @ 109,597,440    524,288   (NB x 8192 u64)
// peak ~110.1 MB (<= 115.7 MB proven safe)

__device__ __forceinline__ u32 skey(float f) {
    u32 u = __float_as_uint(f);
    return (u & 0x80000000u) ? ~u : (u | 0x80000000u);
}

__device__ __forceinline__ float4 anchor_at(int p, int a) {
    const float rv[3] = {0.5f, 1.0f, 2.0f};
    const float sv[3] = {8.0f, 16.0f, 32.0f};
    int ri = a / 3, si = a % 3;
    float s16 = 16.0f * sv[si];
    float hh = s16 * sqrtf(rv[ri]);
    float ww = s16 * sqrtf(1.0f / rv[ri]);
    float bx1 = 8.0f - 0.5f * ww, by1 = 8.0f - 0.5f * hh;
    float bx2 = 8.0f + 0.5f * ww, by2 = 8.0f + 0.5f * hh;
    float sx = (float)((p % WW2) * 16);
    float sy = (float)((p / WW2) * 16);
    return make_float4(sx + bx1, sy + by1, sx + bx2, sy + by2);
}

// LDS slot swizzle for A staging: octet j of row m
__device__ __forceinline__ int lds_slot(int m, int j) {
    return (((m >> 4) * 64) + ((m & 15) ^ ((4 * (j & 1)) | (8 * (j >> 1)))) + (j << 4)) << 3;
}

// ---------------- kernel: split x into f16 hi/lo, transposed [p][c] --------------
// Tile 64c x 64p, block 256 flat; 256B/wave f32 loads, ushort2 (4B/lane) stores.
// grid (60, 8, 4)
__global__ __launch_bounds__(256) void k_split_x2(
    const float* __restrict__ x, _Float16* __restrict__ xh, _Float16* __restrict__ xl)
{
    __shared__ float S[64][65];
    const int zim = blockIdx.z;
    const int p0 = blockIdx.x * 64, c0 = blockIdx.y * 64;
    const int t = threadIdx.x;
    const float* xi = x + (size_t)zim * CC * PP;
    // load: lane p_l = t&63 (coalesced along p), c rows strided
    const int p_l = t & 63, c_b = t >> 6;
#pragma unroll
    for (int i = 0; i < 16; ++i) {
        int c_l = c_b * 16 + i;
        int p = p0 + p_l;
        S[c_l][p_l] = (p < PP) ? xi[(size_t)(c0 + c_l) * PP + p] : 0.f;
    }
    __syncthreads();
    // store: lane c2 = t&31 covers c pair (coalesced 4B along c), p strided
    const int c2 = t & 31, pg = t >> 5;
#pragma unroll
    for (int i = 0; i < 8; ++i) {
        int pl2 = pg * 8 + i;
        int p = p0 + pl2;
        if (p < PP) {
            float v0 = S[2 * c2][pl2];
            float v1 = S[2 * c2 + 1][pl2];
            _Float16 h0 = (_Float16)v0, h1 = (_Float16)v1;
            float r0 = v0 - (float)h0, r1 = v1 - (float)h1;
            union { _Float16 f[2]; u32 u; } uh, ul;
            uh.f[0] = h0; uh.f[1] = h1;
            ul.f[0] = (_Float16)(r0 * 2048.0f); ul.f[1] = (_Float16)(r1 * 2048.0f);
            size_t o = (size_t)(zim * PP + p) * 512 + c0 + 2 * c2;
            *(u32*)(xh + o) = uh.u;
            *(u32*)(xl + o) = ul.u;
        }
    }
}

// ---------------- kernel: split conv1 + head weights (fused) ---------------------
__global__ void k_split_wall(const float* __restrict__ w, _Float16* __restrict__ wh,
                             _Float16* __restrict__ wl,
                             const float* __restrict__ lw, const float* __restrict__ sw,
                             _Float16* __restrict__ wh2, _Float16* __restrict__ wl2) {
    if (blockIdx.x >= 512) {
        int row = blockIdx.x - 512;
        for (int k = threadIdx.x; k < 512; k += 256) {
            float v = (row < 36) ? lw[row * 512 + k]
                                 : (row < 54 ? sw[(row - 36) * 512 + k] : 0.f);
            _Float16 h = (_Float16)v;
            float r = v - (float)h;
            wh2[row * 512 + k] = h;
            wl2[row * 512 + k] = (_Float16)(r * 2048.0f);
        }
        return;
    }
    __shared__ float S[4608];
    int co = blockIdx.x;
    for (int t = threadIdx.x; t < 4608; t += 256) S[t] = w[(size_t)co * 4608 + t];
    __syncthreads();
    int g = co >> 4, nlo = co & 15;
    for (int e = threadIdx.x; e < 4608; e += 256) {
        int cc = e / 9, idx = e - cc * 9;
        float v = S[cc * 9 + idx];
        _Float16 h = (_Float16)v;
        float r = v - (float)h;
        int kk = (cc >> 5) * 9 + idx;
        int lane = ((cc >> 3) & 3) * 16 + nlo;
        int j = cc & 7;
        size_t d = (((size_t)g * 144 + kk) * 64 + lane) * 8 + j;
        wh[d] = h;
        wl[d] = (_Float16)(r * 2048.0f);
    }
}

// ---------------- kernel: 3x3 conv via split-f16 MFMA implicit GEMM --------------
// PROVEN 231us form.  Register-file-bound at 2 blocks/CU.  Do NOT restructure.
__global__ __launch_bounds__(256, 2) void k_conv(
    const _Float16* __restrict__ xh, const _Float16* __restrict__ xl,
    const _Float16* __restrict__ whF, const _Float16* __restrict__ wlF,
    const float* __restrict__ bias, _Float16* __restrict__ fh,
    _Float16* __restrict__ fl, int imgbase)
{
    __shared__ _Float16 lds[2 * 8192];
    const int tid = threadIdx.x;
    const int L = blockIdx.x;
    const int X = L & 7, q = L >> 3;
    const int nt = X & 3;
    const int zim = (X >> 2) * 2 + (q >= 30 ? 1 : 0);
    const int mt = q - (q >= 30 ? 30 : 0);
    const int m0 = mt * 128, n0 = nt * 128;
    const _Float16* xhi = xh + (size_t)zim * CC * PP;
    const _Float16* xlo = xl + (size_t)zim * CC * PP;

    const int mA0 = tid >> 2, jA0 = tid & 3;
    const int mA1 = 64 + (tid >> 2);

    f32x4 acc[4][4], acc2[4][4];
#pragma unroll
    for (int i = 0; i < 4; ++i)
#pragma unroll
        for (int j = 0; j < 4; ++j) {
            acc[i][j] = f32x4{0.f, 0.f, 0.f, 0.f};
            acc2[i][j] = f32x4{0.f, 0.f, 0.f, 0.f};
        }

    uint4 pa0h, pa0l, pa1h, pa1l;

    auto ld_a = [&](int m, int idx, int c0, uint4& vh, uint4& vl) {
        int dy = idx / 3 - 1, dx = idx % 3 - 1;
        int p = m0 + m;
        int px = p % 76, py = p / 76;
        bool av = (p < PP) && ((unsigned)(py + dy) < 50u) && ((unsigned)(px + dx) < 76u);
        if (av) {
            size_t off = (size_t)(p + dy * 76 + dx) * 512 + c0 + jA0 * 8;
            vh = *(const uint4*)(xhi + off);
            vl = *(const uint4*)(xlo + off);
        } else {
            vh = make_uint4(0, 0, 0, 0);
            vl = make_uint4(0, 0, 0, 0);
        }
    };
    auto stage_load = [&](int kk) {
        int c9 = kk / 9;
        int idx = kk - c9 * 9;
        int c0 = c9 << 5;
        ld_a(mA0, idx, c0, pa0h, pa0l);
        ld_a(mA1, idx, c0, pa1h, pa1l);
    };
    const int sl0 = lds_slot(mA0, jA0);
    const int sl1 = lds_slot(mA1, jA0);
    auto stage_write = [&](int buf) {
        _Float16* Lp = lds + buf * 8192;
        *(uint4*)(Lp + sl0)        = pa0h;
        *(uint4*)(Lp + 4096 + sl0) = pa0l;
        *(uint4*)(Lp + sl1)        = pa1h;
        *(uint4*)(Lp + 4096 + sl1) = pa1l;
    };

    const int lane = tid & 63, wave = tid >> 6;
    const int wm = wave & 1, wn = wave >> 1;
    const int jr = lane >> 4;
    const int rd_off = (((lane & 15) ^ ((4 * (jr & 1)) | (8 * (jr >> 1)))) + (jr << 4)) << 3;
    const int g0 = nt * 8 + wn * 4;
    const size_t lane8 = (size_t)lane * 8;

    half8 b0h[4], b0l[4], b1h[4], b1l[4];
    auto load_b = [&](int kk, half8* bh_, half8* bl_) {
#pragma unroll
        for (int ni = 0; ni < 4; ++ni) {
            size_t off = (((size_t)(g0 + ni) * 144 + kk) * 64) * 8 + lane8;
            bh_[ni] = *(const half8*)(whF + off);
            bl_[ni] = *(const half8*)(wlF + off);
        }
    };

    auto compute = [&](int buf, const half8* bh, const half8* bl) {
        const _Float16* Lp = lds + buf * 8192;
        half8 ah[4], al[4];
#pragma unroll
        for (int mi = 0; mi < 4; ++mi) {
            int slot = (((wm * 4 + mi) * 64) << 3) + rd_off;
            ah[mi] = *(const half8*)(Lp + slot);
            al[mi] = *(const half8*)(Lp + 4096 + slot);
        }
#pragma unroll
        for (int ni = 0; ni < 4; ++ni) {
#pragma unroll
            for (int mi = 0; mi < 4; ++mi) {
                acc[mi][ni]  = __builtin_amdgcn_mfma_f32_16x16x32_f16(ah[mi], bh[ni], acc[mi][ni], 0, 0, 0);
                acc2[mi][ni] = __builtin_amdgcn_mfma_f32_16x16x32_f16(ah[mi], bl[ni], acc2[mi][ni], 0, 0, 0);
                acc2[mi][ni] = __builtin_amdgcn_mfma_f32_16x16x32_f16(al[mi], bh[ni], acc2[mi][ni], 0, 0, 0);
            }
        }
    };

    stage_load(0);
    stage_write(0);
    load_b(0, b0h, b0l);
    __syncthreads();
    for (int kk = 0; kk < 144; kk += 2) {
        stage_load(kk + 1);
        load_b(kk + 1, b1h, b1l);
        compute(0, b0h, b0l);
        stage_write(1);
        __syncthreads();
        if (kk + 2 < 144) {
            stage_load(kk + 2);
            load_b(kk + 2, b0h, b0l);
        }
        compute(1, b1h, b1l);
        if (kk + 2 < 144) stage_write(0);
        __syncthreads();
    }

    const int qq = lane >> 4, cl = lane & 15;
    const size_t rowbase = (size_t)(imgbase + zim) * PP;
#pragma unroll
    for (int ni = 0; ni < 4; ++ni) {
        int n = n0 + (wn * 4 + ni) * 16 + cl;
        float bs = bias[n];
#pragma unroll
        for (int mi = 0; mi < 4; ++mi) {
            int mb = m0 + (wm * 4 + mi) * 16 + qq * 4;
            if (mb < PP) {
#pragma unroll
                for (int r = 0; r < 4; ++r) {
                    float v = fmaxf(acc[mi][ni][r] + acc2[mi][ni][r] * (1.f / 2048.f) + bs, 0.f);
                    _Float16 h = (_Float16)v;
                    float rr = v - (float)h;
                    size_t o = (rowbase + mb + r) * 512 + n;
                    fh[o] = h;
                    fl[o] = (_Float16)(rr * 2048.0f);
                }
            }
        }
    }
}

// ---------------- kernel: head GEMM + fused decode (k_post folded in) ------------
__global__ __launch_bounds__(256) void k_hgemm_post(
    const _Float16* __restrict__ fh, const _Float16* __restrict__ fl,
    const _Float16* __restrict__ wh2, const _Float16* __restrict__ wl2,
    const float* __restrict__ lb, const float* __restrict__ sbias,
    const int* __restrict__ imh_p, const int* __restrict__ imw_p,
    float* __restrict__ out0, float* __restrict__ out1,
    float* __restrict__ boxes, float* __restrict__ scores,
    float* __restrict__ out3)
{
    const int img = blockIdx.y;
    const int p0 = blockIdx.x * 64;
    const int wave = threadIdx.x >> 6, lane = threadIdx.x & 63;
    const int q8 = (lane >> 4) * 8;
    int arow = img * PP + p0 + wave * 16 + (lane & 15);
    if (arow >= NB * PP) arow = NB * PP - 1;
    const _Float16* fhp = fh + (size_t)arow * 512 + q8;
    const _Float16* flp = fl + (size_t)arow * 512 + q8;
    const _Float16* bhp = wh2 + (size_t)(lane & 15) * 512 + q8;
    const _Float16* blp = wl2 + (size_t)(lane & 15) * 512 + q8;

    f32x4 acc[4], acc2[4];
#pragma unroll
    for (int j = 0; j < 4; ++j) {
        acc[j] = f32x4{0.f, 0.f, 0.f, 0.f};
        acc2[j] = f32x4{0.f, 0.f, 0.f, 0.f};
    }

#pragma unroll 4
    for (int k0 = 0; k0 < 512; k0 += 32) {
        half8 ah = *(const half8*)(fhp + k0);
        half8 al = *(const half8*)(flp + k0);
#pragma unroll
        for (int nf = 0; nf < 4; ++nf) {
            half8 bh = *(const half8*)(bhp + (size_t)nf * 16 * 512 + k0);
            half8 bl = *(const half8*)(blp + (size_t)nf * 16 * 512 + k0);
            acc[nf]  = __builtin_amdgcn_mfma_f32_16x16x32_f16(ah, bh, acc[nf], 0, 0, 0);
            acc2[nf] = __builtin_amdgcn_mfma_f32_16x16x32_f16(ah, bl, acc2[nf], 0, 0, 0);
            acc2[nf] = __builtin_amdgcn_mfma_f32_16x16x32_f16(al, bh, acc2[nf], 0, 0, 0);
        }
    }

    __shared__ float Ls[64][68];
    const int q = lane >> 4, cl = lane & 15;
#pragma unroll
    for (int nf = 0; nf < 4; ++nf) {
        int n = nf * 16 + cl;
        float bs = (n < 36) ? lb[n] : (n < 54 ? sbias[n - 36] : 0.f);
#pragma unroll
        for (int r = 0; r < 4; ++r) {
            int ml = wave * 16 + q * 4 + r;
            Ls[ml][n] = acc[nf][r] + acc2[nf][r] * (1.f / 2048.f) + bs;
        }
    }
    __syncthreads();

    const float fimh = (float)(*imh_p), fimw = (float)(*imw_p);
    for (int task = threadIdx.x; task < 576; task += 256) {
        int pl = task / 9, a = task - pl * 9;
        int p = p0 + pl;
        if (p >= PP) continue;
        float4 loc = *(const float4*)&Ls[pl][a * 4];
        float2 sc = make_float2(Ls[pl][36 + a * 2], Ls[pl][36 + a * 2 + 1]);
        size_t ai = (size_t)img * NA + (size_t)p * 9 + a;
        *(float4*)&out0[ai * 4] = loc;
        *(float2*)&out1[ai * 2] = sc;
        float mx = fmaxf(sc.x, sc.y);
        float e0 = expf(sc.x - mx), e1 = expf(sc.y - mx);
        float fg = e1 / (e0 + e1);
        float4 an = anchor_at(p, a);
        if (img == 0) ((float4*)out3)[p * 9 + a] = an;
        float aw = an.z - an.x, ah = an.w - an.y;
        float ax = an.x + 0.5f * aw, ay = an.y + 0.5f * ah;
        float cx = loc.x * aw + ax;
        float cy = loc.y * ah + ay;
        float wb = expf(loc.z) * aw, hb = expf(loc.w) * ah;
        float x1 = cx - 0.5f * wb, y1 = cy - 0.5f * hb;
        float x2 = cx + 0.5f * wb, y2 = cy + 0.5f * hb;
        x1 = fminf(fmaxf(x1, 0.f), fimw);
        x2 = fminf(fmaxf(x2, 0.f), fimw);
        y1 = fminf(fmaxf(y1, 0.f), fimh);
        y2 = fminf(fmaxf(y2, 0.f), fimh);
        bool valid = ((x2 - x1) >= 16.0f) && ((y2 - y1) >= 16.0f);
        ((float4*)boxes)[ai] = make_float4(x1, y1, x2, y2);
        scores[ai] = valid ? fg : -INFINITY;
    }
}

// ================= selection: fused 4-pass radix select + collect ================
// grid (8, NB) = 64 blocks (all trivially co-resident -> spin barriers safe).
// Cross-block traffic is exclusively ghist/gpref/grem/gdone/gflag via device-scope
// atomics (per-XCD L2 non-coherence respected); bulk data (arr) is only read by
// the NEXT kernel across a dispatch boundary.
__global__ __launch_bounds__(256) void k_select_all(
    const float* __restrict__ scores, u32* __restrict__ ghist,
    u32* __restrict__ gpref, u32* __restrict__ grem, u32* __restrict__ gdone,
    u32* __restrict__ gflag, u32* __restrict__ gccnt, u64* __restrict__ arr)
{
    __shared__ u32 wh[4][256];
    __shared__ u32 A[256];
    __shared__ u64 lst[4288];
    __shared__ u32 s_c, s_base;
    __shared__ int s_last, s_d;
    const int img = blockIdx.y, blk = blockIdx.x;
    const int tid = threadIdx.x, wv = tid >> 6, lane = tid & 63;
    const float4* sc4 = (const float4*)(scores + (size_t)img * NA);
    const int e40 = blk * SCHUNK;
    const int e41 = min(e40 + SCHUNK, NA / 4);

    for (int pass = 0; pass < 4; ++pass) {
        const int sh = 24 - 8 * pass;
#pragma unroll
        for (int w = 0; w < 4; ++w) wh[w][tid] = 0;
        __syncthreads();
        const u32 pmask = (pass == 0) ? 0u : (0xFFFFFFFFu << (sh + 8));
        const u32 pref = (pass == 0) ? 0u : atomicAdd(&gpref[img], 0u);
        for (int e4 = e40 + tid; e4 < e41; e4 += 256) {
            float4 s4 = sc4[e4];
            u32 kv[4] = {skey(s4.x), skey(s4.y), skey(s4.z), skey(s4.w)};
#pragma unroll
            for (int v = 0; v < 4; ++v)
                if ((kv[v] & pmask) == pref) atomicAdd(&wh[wv][(kv[v] >> sh) & 255u], 1u);
        }
        __syncthreads();
        u32 s = wh[0][tid] + wh[1][tid] + wh[2][tid] + wh[3][tid];
        if (s) atomicAdd(&ghist[img * 256 + tid], s);
        __threadfence();
        __syncthreads();
        if (tid == 0) s_last = (atomicAdd(&gdone[pass * 8 + img], 1u) == 7u) ? 1 : 0;
        __syncthreads();
        if (s_last) {
            u32 h = atomicAdd(&ghist[img * 256 + tid], 0u);
            A[tid] = h;
            if (tid == 0) s_d = 0;
            __syncthreads();
            for (int off = 1; off < 256; off <<= 1) {
                u32 v = A[tid] + ((tid + off < 256) ? A[tid + off] : 0u);
                __syncthreads();
                A[tid] = v;
                __syncthreads();
            }
            const u32 rem = (pass == 0) ? (u32)PRE : atomicAdd(&grem[img], 0u);
            if (A[tid] >= rem) atomicMax(&s_d, tid);
            __syncthreads();
            if (tid == 0) {
                int d = s_d;
                u32 snext = (d < 255) ? A[d + 1] : 0u;
                u32 pv = (pass == 0) ? 0u : atomicAdd(&gpref[img], 0u);
                atomicExch(&gpref[img], pv | ((u32)d << sh));
                atomicExch(&grem[img], rem - snext);
            }
            atomicExch(&ghist[img * 256 + tid], 0u);   // zero for next pass
            __threadfence();
            __syncthreads();
            if (tid == 0) atomicExch(&gflag[pass * 8 + img], 1u);
        }
        // wait for this pass's scan result
        if (tid == 0) { while (atomicAdd(&gflag[pass * 8 + img], 0u) == 0u) {} }
        __syncthreads();
    }

    // ---- collect phase (threshold T now final) ----
    if (tid == 0) s_c = 0;
    __syncthreads();
    const u32 T = atomicAdd(&gpref[img], 0u);
    for (int e4 = e40 + tid; e4 < e41; e4 += 256) {
        float4 s4 = sc4[e4];
        u32 ks[4] = {skey(s4.x), skey(s4.y), skey(s4.z), skey(s4.w)};
#pragma unroll
        for (int v = 0; v < 4; ++v) {
            bool take = ks[v] >= T;
            u64 bal = __ballot(take);
            if (bal) {
                int leader = __builtin_ctzll(bal);
                u32 base = 0;
                if (lane == leader) base = atomicAdd(&s_c, (u32)__popcll(bal));
                base = (u32)__shfl((int)base, leader);
                if (take)
                    lst[base + (u32)__popcll(bal & ((1ull << lane) - 1ull))] =
                        ((u64)ks[v] << 32) | (u64)(~(u32)(e4 * 4 + v));
            }
        }
    }
    __syncthreads();
    if (tid == 0) s_base = atomicAdd(&gccnt[img], s_c);
    __syncthreads();
    const u32 base = s_base, c = s_c;
    u64* ar = arr + (size_t)img * NPAD;
    for (u32 t = tid; t < c; t += 256) {
        u32 pos = base + t;
        if (pos < NPAD) ar[pos] = lst[t];
    }
}

// ---- sub-sort: each block bitonic-sorts one 4096-half descending, in place ------
__global__ __launch_bounds__(1024) void k_sel_sort2(
    u64* __restrict__ arr, const u32* __restrict__ gccnt)
{
    __shared__ u64 a[SHALF];
    const int img = blockIdx.y, half = blockIdx.x;
    const int tid = threadIdx.x;
    u32 n = gccnt[img]; if (n > NPAD) n = NPAD;
    u64* ar = arr + (size_t)img * NPAD + (size_t)half * SHALF;
    const int base = half * SHALF;
    for (int t = tid; t < SHALF; t += 1024)
        a[t] = ((u32)(base + t) < n) ? ar[t] : 0ull;
    for (u32 size = 2; size <= SHALF; size <<= 1) {
        for (u32 stride = size >> 1; stride > 0; stride >>= 1) {
            __syncthreads();
            for (u32 t2 = tid; t2 < SHALF / 2; t2 += 1024) {
                u32 i = 2 * t2 - (t2 & (stride - 1));
                u32 j = i + stride;
                u64 x = a[i], y = a[j];
                bool desc = ((i & size) == 0);
                if (desc ? (x < y) : (x > y)) { a[i] = y; a[j] = x; }
            }
        }
    }
    __syncthreads();
    for (int t = tid; t < SHALF; t += 1024) ar[t] = a[t];
}

// ---- merge: rank-t output via merge-path co-rank over the two sorted halves -----
__global__ __launch_bounds__(1024) void k_sel_merge(
    const float* __restrict__ scores, const float4* __restrict__ boxes,
    const u64* __restrict__ arr,
    float* __restrict__ sb, float4* __restrict__ bbs, float* __restrict__ areas)
{
    const int img = blockIdx.y;
    const int t = blockIdx.x * 1024 + threadIdx.x;
    if (t >= PRE) return;
    const u64* A = arr + (size_t)img * NPAD;
    const u64* B = A + SHALF;
    int lo = (t > SHALF) ? (t - SHALF) : 0;
    int hi = (t < SHALF) ? t : SHALF;
    while (lo < hi) {
        int mid = (lo + hi) >> 1;
        if (A[mid] > B[t - 1 - mid]) lo = mid + 1; else hi = mid;
    }
    const int i = lo, j = t - lo;
    u64 va = (i < SHALF) ? A[i] : 0ull;
    u64 vb = (j < SHALF) ? B[j] : 0ull;
    u64 v = (va > vb) ? va : vb;
    u32 e = ~(u32)v;
    const float* sc = scores + (size_t)img * NA;
    float s = sc[e];
    float4 bx = boxes[(size_t)img * NA + e];
    sb[img * PRE + t] = s;
    bbs[img * PRE + t] = bx;
    areas[img * PRE + t] = (bx.z - bx.x) * (bx.w - bx.y);
}

// ---------------- kernel: NMS scan with FUSED IoU --------------------------------
__global__ __launch_bounds__(256) void k_scan(
    const float* __restrict__ sb, const float4* __restrict__ bbs,
    float* __restrict__ out2)
{
    const int img = blockIdx.x;
    const int tid = threadIdx.x;
    const int lane = tid & 63, wv = tid >> 6;   // 4 waves
    __shared__ u64 alive[94];
    __shared__ int list[POST];
    __shared__ float4 kb[POST];
    __shared__ float ka[POST];
    __shared__ float4 wb4[64];
    __shared__ float wa[64];
    __shared__ u64 rowp[4][64];
    __shared__ u64 wred[4];
    __shared__ int s_n;

    for (int j0 = 0; j0 < 94 * 64; j0 += 256) {
        int j = j0 + tid;
        bool al = (j < PRE) && isfinite(sb[(size_t)img * PRE + j]);
        u64 bal = __ballot(al);
        if (lane == 0) alive[(j0 >> 6) + wv] = bal;
    }
    if (tid == 0) s_n = 0;
    __syncthreads();

    for (int w = 0; w < 94; ++w) {
        int n = s_n;
        if (n >= POST) break;
        if (tid < 64) {
            int j = w * 64 + tid;
            float4 b = (j < PRE) ? bbs[(size_t)img * PRE + j] : make_float4(0, 0, 0, 0);
            wb4[tid] = b;
            wa[tid] = (b.z - b.x) * (b.w - b.y);
        }
        __syncthreads();
        {
            int l = tid & 63, part = tid >> 6;
            float4 bl = wb4[l];
            float al_ = wa[l];
            u64 m = 0;
            int b0 = part * 16;
#pragma unroll 4
            for (int b = b0; b < b0 + 16; ++b) {
                float4 bj = wb4[b];
                float xx1 = fmaxf(bl.x, bj.x), yy1 = fmaxf(bl.y, bj.y);
                float xx2 = fminf(bl.z, bj.z), yy2 = fminf(bl.w, bj.w);
                float iw = fmaxf(xx2 - xx1, 0.f), ih2 = fmaxf(yy2 - yy1, 0.f);
                float inter = iw * ih2;
                float iou = inter / (al_ + wa[b] - inter + 1e-9f);
                if (iou > 0.7f) m |= (1ull << b);
            }
            rowp[part][l] = m;
        }
        u64 loc = 0;
        for (int t = tid; t < n; t += 256) {
            float4 kbx = kb[t];
            float kar = ka[t];
            u64 m = 0;
#pragma unroll 4
            for (int b = 0; b < 64; ++b) {
                float4 bj = wb4[b];
                float xx1 = fmaxf(kbx.x, bj.x), yy1 = fmaxf(kbx.y, bj.y);
                float xx2 = fminf(kbx.z, bj.z), yy2 = fminf(kbx.w, bj.w);
                float iw = fmaxf(xx2 - xx1, 0.f), ih2 = fmaxf(yy2 - yy1, 0.f);
                float inter = iw * ih2;
                float iou = inter / (kar + wa[b] - inter + 1e-9f);
                if (iou > 0.7f) m |= (1ull << b);
            }
            loc |= m;
        }
#pragma unroll
        for (int off = 32; off > 0; off >>= 1)
            loc |= __shfl_down(loc, off);
        if (lane == 0) wred[wv] = loc;
        __syncthreads();
        if (wv == 0) {
            u64 supp = wred[0] | wred[1] | wred[2] | wred[3];
            u64 myrow = rowp[0][lane] | rowp[1][lane] | rowp[2][lane] | rowp[3][lane];
            u64 cur = alive[w] & ~supp;
            u64 keptw = 0;
            while (cur) {
                int b = __builtin_ctzll(cur);
                keptw |= 1ull << b;
                u64 row = __shfl(myrow, b);
                u64 hi = (b >= 63) ? 0ull : (~0ull << (b + 1));
                cur &= ~row & hi;
            }
            if (lane == 0) {
                int nn = n;
                u64 bits = keptw;
                while (bits && nn < POST) {
                    int bb = __builtin_ctzll(bits);
                    bits &= bits - 1;
                    list[nn] = w * 64 + bb;
                    kb[nn] = wb4[bb];
                    ka[nn] = wa[bb];
                    ++nn;
                }
                s_n = nn;
            }
        }
        __syncthreads();
    }
    __syncthreads();
    int n = s_n;
    for (int e = tid; e < POST; e += 256) {
        float4 bx = (e < n) ? bbs[(size_t)img * PRE + list[e]] : make_float4(0, 0, 0, 0);
        *(float4*)&out2[((size_t)img * POST + e) * 4] = bx;
    }
}

extern "C" void kernel_launch(void* const* d_in, const int* in_sizes, int n_in,
                              void* d_out, int out_size, void* d_ws, size_t ws_size,
                              hipStream_t stream)
{
    const float* x     = (const float*)d_in[0];
    const float* w1    = (const float*)d_in[1];
    const float* b1    = (const float*)d_in[2];
    const float* sw    = (const float*)d_in[3];
    const float* sbias = (const float*)d_in[4];
    const float* lw    = (const float*)d_in[5];
    const float* lb    = (const float*)d_in[6];
    const int*   imh   = (const int*)d_in[7];
    const int*   imw   = (const int*)d_in[8];
    float* out = (float*)d_out;
    char* ws = (char*)d_ws;

    _Float16* wh2W = (_Float16*)(ws + 0);
    _Float16* wl2W = (_Float16*)(ws + 65536);
    _Float16* whW  = (_Float16*)(ws + 131072);
    _Float16* wlW  = (_Float16*)(ws + 4849664);
    _Float16* xhW  = (_Float16*)(ws + 9568256);
    _Float16* xlW  = (_Float16*)(ws + 25133056);
    float*    boxesW  = (float*)(ws + 17350656);
    float*    scoresW = (float*)(ws + 21728256);
    float*    sbW     = (float*)(ws + 22822656);
    float*    bbsW    = (float*)(ws + 23014656);
    float*    areasW  = (float*)(ws + 23782656);
    _Float16* fhW  = (_Float16*)(ws + 40697856);
    _Float16* flW  = (_Float16*)(ws + 71827456);
    u32*      ghistW  = (u32*)(ws + 109581056);
    u32*      gccntW  = (u32*)(ws + 109589248);
    u32*      gprefW  = (u32*)(ws + 109589280);
    u32*      gremW   = (u32*)(ws + 109589312);
    u32*      gdoneW  = (u32*)(ws + 109589344);
    u32*      gflagW  = (u32*)(ws + 109589472);
    u64*      arrW    = (u64*)(ws + 109597440);

    float* out0 = out;            // rpn_locs   (8,34200,4)
    float* out1 = out + 1094400;  // rpn_scores (8,34200,2)
    float* out2 = out + 1641600;  // rois       (2400,4)
    float* out3 = out + 1651200;  // anchors    (34200,4)

    // zero select control state (ghist | gccnt | gpref | grem | gdone | gflag)
    hipMemsetAsync(ws + 109581056, 0, 8544, stream);

    hipLaunchKernelGGL(k_split_wall, dim3(576), dim3(256), 0, stream,
                       w1, whW, wlW, lw, sw, wh2W, wl2W);
    for (int b = 0; b < 2; ++b) {
        hipLaunchKernelGGL(k_split_x2, dim3(60, 8, 4), dim3(256), 0, stream,
                           x + (size_t)b * 4 * CC * PP, xhW, xlW);
        hipLaunchKernelGGL(k_conv, dim3(480), dim3(256), 0, stream,
                           xhW, xlW, whW, wlW, b1, fhW, flW, b * 4);
    }
    hipLaunchKernelGGL(k_hgemm_post, dim3(60, NB), dim3(256), 0, stream,
                       fhW, flW, wh2W, wl2W, lb, sbias, imh, imw,
                       out0, out1, boxesW, scoresW, out3);
    hipLaunchKernelGGL(k_select_all, dim3(8, NB), dim3(256), 0, stream,
                       scoresW, ghistW, gprefW, gremW, gdoneW, gflagW,
                       gccntW, arrW);
    hipLaunchKernelGGL(k_sel_sort2, dim3(2, NB), dim3(1024), 0, stream,
                       arrW, gccntW);
    hipLaunchKernelGGL(k_sel_merge, dim3((PRE + 1023) / 1024, NB), dim3(1024), 0, stream,
                       scoresW, (const float4*)boxesW, arrW,
                       sbW, (float4*)bbsW, areasW);
    hipLaunchKernelGGL(k_scan, dim3(NB), dim3(256), 0, stream,
                       sbW, (const float4*)bbsW, out2);
}

// Round 13
// 821.791 us; speedup vs baseline: 1.0118x; 1.0118x over previous
//
#include <hip/hip_runtime.h>
#include <stdint.h>
#include <math.h>

typedef unsigned long long u64;
typedef unsigned int u32;
typedef _Float16 half8 __attribute__((ext_vector_type(8)));
typedef float f32x4 __attribute__((ext_vector_type(4)));

#define CC   512
#define HH   50
#define WW2  76
#define PP   3800      // HH*WW2
#define NB   8
#define NA   34200     // PP*9
#define PRE  6000
#define POST 300
#define NPAD 8192      // candidate buffer size per image
#define SHALF 4096     // per-block bitonic sort size (NPAD/2)
#define SCHUNK 1069    // float4-chunks per select block (8 blocks x 1069 >= 8550)

// ---------------- workspace layout (bytes) ----------------
// wh2   @ 0            65,536      (64 x 512 f16)  [head weights hi]
// wl2   @ 65,536       65,536
// whF   @ 131,072      4,718,592   (frag-major conv weights hi: [g][kk][lane][8])
// wlF   @ 4,849,664    4,718,592
// xh    @ 9,568,256    15,564,800  (4 img * 3800 * 512 f16, per-batch)
// xl    @ 25,133,056   15,564,800
// --- after conv, xh/xl dead; overlay: ---
// boxes @ 17,350,656   4,377,600
// scores@ 21,728,256   1,094,400
// sb    @ 22,822,656     192,000
// bbs   @ 23,014,656     768,000
// areas @ 23,782,656     192,000
// fh    @ 40,697,856   31,129,600
// fl    @ 71,827,456   31,129,600
// selst @ 109,581,056     16,384   (ghist 8192 | gccnt | gpref | grem | gdone)
// arr   @ 109,597,440    524,288   (NB x 8192 u64)
// peak ~110.1 MB (<= 115.7 MB proven safe)

__device__ __forceinline__ u32 skey(float f) {
    u32 u = __float_as_uint(f);
    return (u & 0x80000000u) ? ~u : (u | 0x80000000u);
}

__device__ __forceinline__ float4 anchor_at(int p, int a) {
    const float rv[3] = {0.5f, 1.0f, 2.0f};
    const float sv[3] = {8.0f, 16.0f, 32.0f};
    int ri = a / 3, si = a % 3;
    float s16 = 16.0f * sv[si];
    float hh = s16 * sqrtf(rv[ri]);
    float ww = s16 * sqrtf(1.0f / rv[ri]);
    float bx1 = 8.0f - 0.5f * ww, by1 = 8.0f - 0.5f * hh;
    float bx2 = 8.0f + 0.5f * ww, by2 = 8.0f + 0.5f * hh;
    float sx = (float)((p % WW2) * 16);
    float sy = (float)((p / WW2) * 16);
    return make_float4(sx + bx1, sy + by1, sx + bx2, sy + by2);
}

// LDS slot swizzle for A staging: octet j of row m
__device__ __forceinline__ int lds_slot(int m, int j) {
    return (((m >> 4) * 64) + ((m & 15) ^ ((4 * (j & 1)) | (8 * (j >> 1)))) + (j << 4)) << 3;
}

// ---------------- kernel: split x into f16 hi/lo, transposed [p][c] --------------
// grid (119, 16, 4), block (32,8)
__global__ void k_split_x(const float* __restrict__ x, _Float16* __restrict__ xh,
                          _Float16* __restrict__ xl) {
    __shared__ float S[32][33];
    int zim = blockIdx.z;
    int p0 = blockIdx.x * 32, c0 = blockIdx.y * 32;
    int tx = threadIdx.x, ty0 = threadIdx.y;
    const float* xi = x + (size_t)zim * CC * PP;
#pragma unroll
    for (int yy = 0; yy < 32; yy += 8) {
        int cty = c0 + ty0 + yy, ptx = p0 + tx;
        S[ty0 + yy][tx] = (ptx < PP) ? xi[(size_t)cty * PP + ptx] : 0.f;
    }
    __syncthreads();
#pragma unroll
    for (int yy = 0; yy < 32; yy += 8) {
        int p = p0 + ty0 + yy;
        if (p < PP) {
            float v = S[tx][ty0 + yy];
            _Float16 h = (_Float16)v;
            float r = v - (float)h;
            size_t o = (size_t)(zim * PP + p) * 512 + c0 + tx;
            xh[o] = h;
            xl[o] = (_Float16)(r * 2048.0f);
        }
    }
}

// ---------------- kernel: split conv1 + head weights (fused) ---------------------
// blocks 0..511: conv weights -> frag-major hi/lo.
// blocks 512..575: head weights row (block-512) -> [64][512] hi/lo.
__global__ void k_split_wall(const float* __restrict__ w, _Float16* __restrict__ wh,
                             _Float16* __restrict__ wl,
                             const float* __restrict__ lw, const float* __restrict__ sw,
                             _Float16* __restrict__ wh2, _Float16* __restrict__ wl2) {
    if (blockIdx.x >= 512) {
        int row = blockIdx.x - 512;
        for (int k = threadIdx.x; k < 512; k += 256) {
            float v = (row < 36) ? lw[row * 512 + k]
                                 : (row < 54 ? sw[(row - 36) * 512 + k] : 0.f);
            _Float16 h = (_Float16)v;
            float r = v - (float)h;
            wh2[row * 512 + k] = h;
            wl2[row * 512 + k] = (_Float16)(r * 2048.0f);
        }
        return;
    }
    __shared__ float S[4608];
    int co = blockIdx.x;
    for (int t = threadIdx.x; t < 4608; t += 256) S[t] = w[(size_t)co * 4608 + t];
    __syncthreads();
    int g = co >> 4, nlo = co & 15;
    for (int e = threadIdx.x; e < 4608; e += 256) {
        int cc = e / 9, idx = e - cc * 9;          // e enumerates (ci, idx)
        float v = S[cc * 9 + idx];
        _Float16 h = (_Float16)v;
        float r = v - (float)h;
        int kk = (cc >> 5) * 9 + idx;
        int lane = ((cc >> 3) & 3) * 16 + nlo;
        int j = cc & 7;
        size_t d = (((size_t)g * 144 + kk) * 64 + lane) * 8 + j;
        wh[d] = h;
        wl[d] = (_Float16)(r * 2048.0f);
    }
}

// ---------------- kernel: 3x3 conv via split-f16 MFMA implicit GEMM --------------
// 1-D grid 480 (XCD-pinned), block 256 (4 waves, 2x2), BM=BN=128, BK=32.
// PROVEN 231us form.  Register-file-bound at 2 blocks/CU (128 VGPR + 128 AGPR acc).
// Final verdict: do NOT restructure (round-6 spill 7.7x; round-9 big-LDS pipeline
// killed the container).  This is the 2-phase structure's ceiling (~941 TF eff).
__global__ __launch_bounds__(256, 2) void k_conv(
    const _Float16* __restrict__ xh, const _Float16* __restrict__ xl,
    const _Float16* __restrict__ whF, const _Float16* __restrict__ wlF,
    const float* __restrict__ bias, _Float16* __restrict__ fh,
    _Float16* __restrict__ fl, int imgbase)
{
    __shared__ _Float16 lds[2 * 8192];
    const int tid = threadIdx.x;
    const int L = blockIdx.x;
    const int X = L & 7, q = L >> 3;          // q in 0..59
    const int nt = X & 3;
    const int zim = (X >> 2) * 2 + (q >= 30 ? 1 : 0);
    const int mt = q - (q >= 30 ? 30 : 0);
    const int m0 = mt * 128, n0 = nt * 128;
    const _Float16* xhi = xh + (size_t)zim * CC * PP;
    const _Float16* xlo = xl + (size_t)zim * CC * PP;

    const int mA0 = tid >> 2, jA0 = tid & 3;
    const int mA1 = 64 + (tid >> 2);

    f32x4 acc[4][4], acc2[4][4];
#pragma unroll
    for (int i = 0; i < 4; ++i)
#pragma unroll
        for (int j = 0; j < 4; ++j) {
            acc[i][j] = f32x4{0.f, 0.f, 0.f, 0.f};
            acc2[i][j] = f32x4{0.f, 0.f, 0.f, 0.f};
        }

    uint4 pa0h, pa0l, pa1h, pa1l;

    auto ld_a = [&](int m, int idx, int c0, uint4& vh, uint4& vl) {
        int dy = idx / 3 - 1, dx = idx % 3 - 1;
        int p = m0 + m;
        int px = p % 76, py = p / 76;
        bool av = (p < PP) && ((unsigned)(py + dy) < 50u) && ((unsigned)(px + dx) < 76u);
        if (av) {
            size_t off = (size_t)(p + dy * 76 + dx) * 512 + c0 + jA0 * 8;
            vh = *(const uint4*)(xhi + off);
            vl = *(const uint4*)(xlo + off);
        } else {
            vh = make_uint4(0, 0, 0, 0);
            vl = make_uint4(0, 0, 0, 0);
        }
    };
    auto stage_load = [&](int kk) {
        int c9 = kk / 9;                   // c-chunk outer, idx inner
        int idx = kk - c9 * 9;
        int c0 = c9 << 5;
        ld_a(mA0, idx, c0, pa0h, pa0l);
        ld_a(mA1, idx, c0, pa1h, pa1l);
    };
    const int sl0 = lds_slot(mA0, jA0);
    const int sl1 = lds_slot(mA1, jA0);
    auto stage_write = [&](int buf) {
        _Float16* Lp = lds + buf * 8192;
        *(uint4*)(Lp + sl0)        = pa0h;
        *(uint4*)(Lp + 4096 + sl0) = pa0l;
        *(uint4*)(Lp + sl1)        = pa1h;
        *(uint4*)(Lp + 4096 + sl1) = pa1l;
    };

    const int lane = tid & 63, wave = tid >> 6;
    const int wm = wave & 1, wn = wave >> 1;
    const int jr = lane >> 4;
    const int rd_off = (((lane & 15) ^ ((4 * (jr & 1)) | (8 * (jr >> 1)))) + (jr << 4)) << 3;
    const int g0 = nt * 8 + wn * 4;                 // base B frag index
    const size_t lane8 = (size_t)lane * 8;

    half8 b0h[4], b0l[4], b1h[4], b1l[4];
    auto load_b = [&](int kk, half8* bh_, half8* bl_) {
#pragma unroll
        for (int ni = 0; ni < 4; ++ni) {
            size_t off = (((size_t)(g0 + ni) * 144 + kk) * 64) * 8 + lane8;
            bh_[ni] = *(const half8*)(whF + off);
            bl_[ni] = *(const half8*)(wlF + off);
        }
    };

    auto compute = [&](int buf, const half8* bh, const half8* bl) {
        const _Float16* Lp = lds + buf * 8192;
        half8 ah[4], al[4];
#pragma unroll
        for (int mi = 0; mi < 4; ++mi) {
            int slot = (((wm * 4 + mi) * 64) << 3) + rd_off;
            ah[mi] = *(const half8*)(Lp + slot);
            al[mi] = *(const half8*)(Lp + 4096 + slot);
        }
#pragma unroll
        for (int ni = 0; ni < 4; ++ni) {
#pragma unroll
            for (int mi = 0; mi < 4; ++mi) {
                acc[mi][ni]  = __builtin_amdgcn_mfma_f32_16x16x32_f16(ah[mi], bh[ni], acc[mi][ni], 0, 0, 0);
                acc2[mi][ni] = __builtin_amdgcn_mfma_f32_16x16x32_f16(ah[mi], bl[ni], acc2[mi][ni], 0, 0, 0);
                acc2[mi][ni] = __builtin_amdgcn_mfma_f32_16x16x32_f16(al[mi], bh[ni], acc2[mi][ni], 0, 0, 0);
            }
        }
    };

    stage_load(0);
    stage_write(0);
    load_b(0, b0h, b0l);
    __syncthreads();
    // K loop unrolled by 2: explicit register ping-pong for B (no copies)
    for (int kk = 0; kk < 144; kk += 2) {
        // chunk kk (A buf = 0)
        stage_load(kk + 1);
        load_b(kk + 1, b1h, b1l);
        compute(0, b0h, b0l);
        stage_write(1);
        __syncthreads();
        // chunk kk+1 (A buf = 1)
        if (kk + 2 < 144) {
            stage_load(kk + 2);
            load_b(kk + 2, b0h, b0l);
        }
        compute(1, b1h, b1l);
        if (kk + 2 < 144) stage_write(0);
        __syncthreads();
    }

    const int qq = lane >> 4, cl = lane & 15;
    const size_t rowbase = (size_t)(imgbase + zim) * PP;
#pragma unroll
    for (int ni = 0; ni < 4; ++ni) {
        int n = n0 + (wn * 4 + ni) * 16 + cl;
        float bs = bias[n];
#pragma unroll
        for (int mi = 0; mi < 4; ++mi) {
            int mb = m0 + (wm * 4 + mi) * 16 + qq * 4;
            if (mb < PP) {
#pragma unroll
                for (int r = 0; r < 4; ++r) {
                    float v = fmaxf(acc[mi][ni][r] + acc2[mi][ni][r] * (1.f / 2048.f) + bs, 0.f);
                    _Float16 h = (_Float16)v;
                    float rr = v - (float)h;
                    size_t o = (rowbase + mb + r) * 512 + n;
                    fh[o] = h;
                    fl[o] = (_Float16)(rr * 2048.0f);
                }
            }
        }
    }
}

// ---------------- kernel: head GEMM + fused decode (k_post folded in) ------------
__global__ __launch_bounds__(256) void k_hgemm_post(
    const _Float16* __restrict__ fh, const _Float16* __restrict__ fl,
    const _Float16* __restrict__ wh2, const _Float16* __restrict__ wl2,
    const float* __restrict__ lb, const float* __restrict__ sbias,
    const int* __restrict__ imh_p, const int* __restrict__ imw_p,
    float* __restrict__ out0, float* __restrict__ out1,
    float* __restrict__ boxes, float* __restrict__ scores,
    float* __restrict__ out3)
{
    const int img = blockIdx.y;
    const int p0 = blockIdx.x * 64;
    const int wave = threadIdx.x >> 6, lane = threadIdx.x & 63;
    const int q8 = (lane >> 4) * 8;
    int arow = img * PP + p0 + wave * 16 + (lane & 15);
    if (arow >= NB * PP) arow = NB * PP - 1;
    const _Float16* fhp = fh + (size_t)arow * 512 + q8;
    const _Float16* flp = fl + (size_t)arow * 512 + q8;
    const _Float16* bhp = wh2 + (size_t)(lane & 15) * 512 + q8;
    const _Float16* blp = wl2 + (size_t)(lane & 15) * 512 + q8;

    f32x4 acc[4], acc2[4];
#pragma unroll
    for (int j = 0; j < 4; ++j) {
        acc[j] = f32x4{0.f, 0.f, 0.f, 0.f};
        acc2[j] = f32x4{0.f, 0.f, 0.f, 0.f};
    }

#pragma unroll 4
    for (int k0 = 0; k0 < 512; k0 += 32) {
        half8 ah = *(const half8*)(fhp + k0);
        half8 al = *(const half8*)(flp + k0);
#pragma unroll
        for (int nf = 0; nf < 4; ++nf) {
            half8 bh = *(const half8*)(bhp + (size_t)nf * 16 * 512 + k0);
            half8 bl = *(const half8*)(blp + (size_t)nf * 16 * 512 + k0);
            acc[nf]  = __builtin_amdgcn_mfma_f32_16x16x32_f16(ah, bh, acc[nf], 0, 0, 0);
            acc2[nf] = __builtin_amdgcn_mfma_f32_16x16x32_f16(ah, bl, acc2[nf], 0, 0, 0);
            acc2[nf] = __builtin_amdgcn_mfma_f32_16x16x32_f16(al, bh, acc2[nf], 0, 0, 0);
        }
    }

    // stage the 64x64 O tile to LDS
    __shared__ float Ls[64][68];
    const int q = lane >> 4, cl = lane & 15;
#pragma unroll
    for (int nf = 0; nf < 4; ++nf) {
        int n = nf * 16 + cl;
        float bs = (n < 36) ? lb[n] : (n < 54 ? sbias[n - 36] : 0.f);
#pragma unroll
        for (int r = 0; r < 4; ++r) {
            int ml = wave * 16 + q * 4 + r;
            Ls[ml][n] = acc[nf][r] + acc2[nf][r] * (1.f / 2048.f) + bs;
        }
    }
    __syncthreads();

    // decode: 64 rows x 9 anchors = 576 tasks over 256 threads
    const float fimh = (float)(*imh_p), fimw = (float)(*imw_p);
    for (int task = threadIdx.x; task < 576; task += 256) {
        int pl = task / 9, a = task - pl * 9;
        int p = p0 + pl;
        if (p >= PP) continue;
        float4 loc = *(const float4*)&Ls[pl][a * 4];
        float2 sc = make_float2(Ls[pl][36 + a * 2], Ls[pl][36 + a * 2 + 1]);
        size_t ai = (size_t)img * NA + (size_t)p * 9 + a;
        *(float4*)&out0[ai * 4] = loc;
        *(float2*)&out1[ai * 2] = sc;
        float mx = fmaxf(sc.x, sc.y);
        float e0 = expf(sc.x - mx), e1 = expf(sc.y - mx);
        float fg = e1 / (e0 + e1);
        float4 an = anchor_at(p, a);
        if (img == 0) ((float4*)out3)[p * 9 + a] = an;
        float aw = an.z - an.x, ah = an.w - an.y;
        float ax = an.x + 0.5f * aw, ay = an.y + 0.5f * ah;
        float cx = loc.x * aw + ax;
        float cy = loc.y * ah + ay;
        float wb = expf(loc.z) * aw, hb = expf(loc.w) * ah;
        float x1 = cx - 0.5f * wb, y1 = cy - 0.5f * hb;
        float x2 = cx + 0.5f * wb, y2 = cy + 0.5f * hb;
        x1 = fminf(fmaxf(x1, 0.f), fimw);
        x2 = fminf(fmaxf(x2, 0.f), fimw);
        y1 = fminf(fmaxf(y1, 0.f), fimh);
        y2 = fminf(fmaxf(y2, 0.f), fimh);
        bool valid = ((x2 - x1) >= 16.0f) && ((y2 - y1) >= 16.0f);
        ((float4*)boxes)[ai] = make_float4(x1, y1, x2, y2);
        scores[ai] = valid ? fg : -INFINITY;
    }
}

// ================= selection pipeline ============================================

// ---- fused histogram + scan: per-wave LDS hist -> global atomics; the LAST
// block per image (threadfence+ticket) runs the 256-bin suffix-scan inline. -----
__global__ __launch_bounds__(256) void k_sel_histscan(
    const float* __restrict__ scores, u32* __restrict__ ghist,
    u32* __restrict__ gpref, u32* __restrict__ grem, u32* __restrict__ gdone,
    int sh, int pass)
{
    __shared__ u32 wh[4][256];
    __shared__ u32 A[256];
    __shared__ int s_last, s_d;
    const int img = blockIdx.y, blk = blockIdx.x;
    const int tid = threadIdx.x, wv = tid >> 6;
#pragma unroll
    for (int w = 0; w < 4; ++w) wh[w][tid] = 0;
    __syncthreads();
    const u32 pmask = (pass == 0) ? 0u : (0xFFFFFFFFu << (sh + 8));
    const u32 pref = (pass == 0) ? 0u : gpref[img];
    const float4* sc4 = (const float4*)(scores + (size_t)img * NA);
    const int e40 = blk * SCHUNK;
    const int e41 = min(e40 + SCHUNK, NA / 4);
    for (int e4 = e40 + tid; e4 < e41; e4 += 256) {
        float4 s4 = sc4[e4];
        u32 kv[4] = {skey(s4.x), skey(s4.y), skey(s4.z), skey(s4.w)};
#pragma unroll
        for (int v = 0; v < 4; ++v)
            if ((kv[v] & pmask) == pref) atomicAdd(&wh[wv][(kv[v] >> sh) & 255u], 1u);
    }
    __syncthreads();
    u32 s = wh[0][tid] + wh[1][tid] + wh[2][tid] + wh[3][tid];
    if (s) atomicAdd(&ghist[img * 256 + tid], s);
    __threadfence();
    __syncthreads();
    if (tid == 0) s_last = (atomicAdd(&gdone[pass * 8 + img], 1u) == 7u) ? 1 : 0;
    __syncthreads();
    if (!s_last) return;
    u32 h = atomicAdd(&ghist[img * 256 + tid], 0u);   // coherent read
    A[tid] = h;
    if (tid == 0) s_d = 0;
    __syncthreads();
    for (int off = 1; off < 256; off <<= 1) {
        u32 v = A[tid] + ((tid + off < 256) ? A[tid + off] : 0u);
        __syncthreads();
        A[tid] = v;
        __syncthreads();
    }
    const u32 rem = (pass == 0) ? (u32)PRE : grem[img];
    if (A[tid] >= rem) atomicMax(&s_d, tid);
    __syncthreads();
    if (tid == 0) {
        int d = s_d;
        u32 snext = (d < 255) ? A[d + 1] : 0u;
        u32 pv = (pass == 0) ? 0u : gpref[img];
        gpref[img] = pv | ((u32)d << sh);
        grem[img] = rem - snext;
    }
    ghist[img * 256 + tid] = 0;    // visible to next pass via kernel boundary
}

// ---- collect: block-local LDS compaction, one global atomic per block -----------
__global__ __launch_bounds__(256) void k_sel_collect(
    const float* __restrict__ scores, const u32* __restrict__ gpref,
    u32* __restrict__ gccnt, u64* __restrict__ arr)
{
    __shared__ u64 lst[4288];
    __shared__ u32 s_c, s_base;
    const int img = blockIdx.y, blk = blockIdx.x;
    const int tid = threadIdx.x, lane = tid & 63;
    if (tid == 0) s_c = 0;
    __syncthreads();
    const u32 T = gpref[img];
    const float4* sc4 = (const float4*)(scores + (size_t)img * NA);
    const int e40 = blk * SCHUNK;
    const int e41 = min(e40 + SCHUNK, NA / 4);
    for (int e4 = e40 + tid; e4 < e41; e4 += 256) {
        float4 s4 = sc4[e4];
        u32 ks[4] = {skey(s4.x), skey(s4.y), skey(s4.z), skey(s4.w)};
#pragma unroll
        for (int v = 0; v < 4; ++v) {
            bool take = ks[v] >= T;
            u64 bal = __ballot(take);
            if (bal) {
                int leader = __builtin_ctzll(bal);
                u32 base = 0;
                if (lane == leader) base = atomicAdd(&s_c, (u32)__popcll(bal));
                base = (u32)__shfl((int)base, leader);
                if (take)
                    lst[base + (u32)__popcll(bal & ((1ull << lane) - 1ull))] =
                        ((u64)ks[v] << 32) | (u64)(~(u32)(e4 * 4 + v));
            }
        }
    }
    __syncthreads();
    if (tid == 0) s_base = atomicAdd(&gccnt[img], s_c);
    __syncthreads();
    const u32 base = s_base, c = s_c;
    u64* ar = arr + (size_t)img * NPAD;
    for (u32 t = tid; t < c; t += 256) {
        u32 pos = base + t;
        if (pos < NPAD) ar[pos] = lst[t];
    }
}

// ---- sub-sort: each block bitonic-sorts one 4096-half descending, in place ------
__global__ __launch_bounds__(1024) void k_sel_sort2(
    u64* __restrict__ arr, const u32* __restrict__ gccnt)
{
    __shared__ u64 a[SHALF];
    const int img = blockIdx.y, half = blockIdx.x;
    const int tid = threadIdx.x;
    u32 n = gccnt[img]; if (n > NPAD) n = NPAD;
    u64* ar = arr + (size_t)img * NPAD + (size_t)half * SHALF;
    const int base = half * SHALF;
    for (int t = tid; t < SHALF; t += 1024)
        a[t] = ((u32)(base + t) < n) ? ar[t] : 0ull;
    for (u32 size = 2; size <= SHALF; size <<= 1) {
        for (u32 stride = size >> 1; stride > 0; stride >>= 1) {
            __syncthreads();
            for (u32 t2 = tid; t2 < SHALF / 2; t2 += 1024) {
                u32 i = 2 * t2 - (t2 & (stride - 1));
                u32 j = i + stride;
                u64 x = a[i], y = a[j];
                bool desc = ((i & size) == 0);
                if (desc ? (x < y) : (x > y)) { a[i] = y; a[j] = x; }
            }
        }
    }
    __syncthreads();
    for (int t = tid; t < SHALF; t += 1024) ar[t] = a[t];
}

// ---- merge: rank-t output via merge-path co-rank over the two sorted halves -----
__global__ __launch_bounds__(1024) void k_sel_merge(
    const float* __restrict__ scores, const float4* __restrict__ boxes,
    const u64* __restrict__ arr,
    float* __restrict__ sb, float4* __restrict__ bbs, float* __restrict__ areas)
{
    const int img = blockIdx.y;
    const int t = blockIdx.x * 1024 + threadIdx.x;
    if (t >= PRE) return;
    const u64* A = arr + (size_t)img * NPAD;
    const u64* B = A + SHALF;
    int lo = (t > SHALF) ? (t - SHALF) : 0;
    int hi = (t < SHALF) ? t : SHALF;
    while (lo < hi) {
        int mid = (lo + hi) >> 1;
        if (A[mid] > B[t - 1 - mid]) lo = mid + 1; else hi = mid;
    }
    const int i = lo, j = t - lo;
    u64 va = (i < SHALF) ? A[i] : 0ull;
    u64 vb = (j < SHALF) ? B[j] : 0ull;
    u64 v = (va > vb) ? va : vb;
    u32 e = ~(u32)v;
    const float* sc = scores + (size_t)img * NA;
    float s = sc[e];
    float4 bx = boxes[(size_t)img * NA + e];
    sb[img * PRE + t] = s;
    bbs[img * PRE + t] = bx;
    areas[img * PRE + t] = (bx.z - bx.x) * (bx.w - bx.y);
}

// ---------------- kernel: NMS scan with FUSED IoU (k_mask eliminated) ------------
__global__ __launch_bounds__(256) void k_scan(
    const float* __restrict__ sb, const float4* __restrict__ bbs,
    float* __restrict__ out2)
{
    const int img = blockIdx.x;
    const int tid = threadIdx.x;
    const int lane = tid & 63, wv = tid >> 6;   // 4 waves
    __shared__ u64 alive[94];
    __shared__ int list[POST];
    __shared__ float4 kb[POST];
    __shared__ float ka[POST];
    __shared__ float4 wb4[64];
    __shared__ float wa[64];
    __shared__ u64 rowp[4][64];
    __shared__ u64 wred[4];
    __shared__ int s_n;

    for (int j0 = 0; j0 < 94 * 64; j0 += 256) {
        int j = j0 + tid;
        bool al = (j < PRE) && isfinite(sb[(size_t)img * PRE + j]);
        u64 bal = __ballot(al);
        if (lane == 0) alive[(j0 >> 6) + wv] = bal;
    }
    if (tid == 0) s_n = 0;
    __syncthreads();

    for (int w = 0; w < 94; ++w) {
        int n = s_n;
        if (n >= POST) break;
        if (tid < 64) {
            int j = w * 64 + tid;
            float4 b = (j < PRE) ? bbs[(size_t)img * PRE + j] : make_float4(0, 0, 0, 0);
            wb4[tid] = b;
            wa[tid] = (b.z - b.x) * (b.w - b.y);
        }
        __syncthreads();
        {
            int l = tid & 63, part = tid >> 6;
            float4 bl = wb4[l];
            float al_ = wa[l];
            u64 m = 0;
            int b0 = part * 16;
#pragma unroll 4
            for (int b = b0; b < b0 + 16; ++b) {
                float4 bj = wb4[b];
                float xx1 = fmaxf(bl.x, bj.x), yy1 = fmaxf(bl.y, bj.y);
                float xx2 = fminf(bl.z, bj.z), yy2 = fminf(bl.w, bj.w);
                float iw = fmaxf(xx2 - xx1, 0.f), ih2 = fmaxf(yy2 - yy1, 0.f);
                float inter = iw * ih2;
                float iou = inter / (al_ + wa[b] - inter + 1e-9f);
                if (iou > 0.7f) m |= (1ull << b);
            }
            rowp[part][l] = m;
        }
        u64 loc = 0;
        for (int t = tid; t < n; t += 256) {
            float4 kbx = kb[t];
            float kar = ka[t];
            u64 m = 0;
#pragma unroll 4
            for (int b = 0; b < 64; ++b) {
                float4 bj = wb4[b];
                float xx1 = fmaxf(kbx.x, bj.x), yy1 = fmaxf(kbx.y, bj.y);
                float xx2 = fminf(kbx.z, bj.z), yy2 = fminf(kbx.w, bj.w);
                float iw = fmaxf(xx2 - xx1, 0.f), ih2 = fmaxf(yy2 - yy1, 0.f);
                float inter = iw * ih2;
                float iou = inter / (kar + wa[b] - inter + 1e-9f);
                if (iou > 0.7f) m |= (1ull << b);
            }
            loc |= m;
        }
#pragma unroll
        for (int off = 32; off > 0; off >>= 1)
            loc |= __shfl_down(loc, off);
        if (lane == 0) wred[wv] = loc;
        __syncthreads();
        if (wv == 0) {
            u64 supp = wred[0] | wred[1] | wred[2] | wred[3];
            u64 myrow = rowp[0][lane] | rowp[1][lane] | rowp[2][lane] | rowp[3][lane];
            u64 cur = alive[w] & ~supp;
            u64 keptw = 0;
            while (cur) {
                int b = __builtin_ctzll(cur);
                keptw |= 1ull << b;
                u64 row = __shfl(myrow, b);
                u64 hi = (b >= 63) ? 0ull : (~0ull << (b + 1));
                cur &= ~row & hi;
            }
            if (lane == 0) {
                int nn = n;
                u64 bits = keptw;
                while (bits && nn < POST) {
                    int bb = __builtin_ctzll(bits);
                    bits &= bits - 1;
                    list[nn] = w * 64 + bb;
                    kb[nn] = wb4[bb];
                    ka[nn] = wa[bb];
                    ++nn;
                }
                s_n = nn;
            }
        }
        __syncthreads();
    }
    __syncthreads();
    int n = s_n;
    for (int e = tid; e < POST; e += 256) {
        float4 bx = (e < n) ? bbs[(size_t)img * PRE + list[e]] : make_float4(0, 0, 0, 0);
        *(float4*)&out2[((size_t)img * POST + e) * 4] = bx;
    }
}

extern "C" void kernel_launch(void* const* d_in, const int* in_sizes, int n_in,
                              void* d_out, int out_size, void* d_ws, size_t ws_size,
                              hipStream_t stream)
{
    const float* x     = (const float*)d_in[0];
    const float* w1    = (const float*)d_in[1];
    const float* b1    = (const float*)d_in[2];
    const float* sw    = (const float*)d_in[3];
    const float* sbias = (const float*)d_in[4];
    const float* lw    = (const float*)d_in[5];
    const float* lb    = (const float*)d_in[6];
    const int*   imh   = (const int*)d_in[7];
    const int*   imw   = (const int*)d_in[8];
    float* out = (float*)d_out;
    char* ws = (char*)d_ws;

    _Float16* wh2W = (_Float16*)(ws + 0);
    _Float16* wl2W = (_Float16*)(ws + 65536);
    _Float16* whW  = (_Float16*)(ws + 131072);
    _Float16* wlW  = (_Float16*)(ws + 4849664);
    _Float16* xhW  = (_Float16*)(ws + 9568256);
    _Float16* xlW  = (_Float16*)(ws + 25133056);
    float*    boxesW  = (float*)(ws + 17350656);
    float*    scoresW = (float*)(ws + 21728256);
    float*    sbW     = (float*)(ws + 22822656);
    float*    bbsW    = (float*)(ws + 23014656);
    float*    areasW  = (float*)(ws + 23782656);
    _Float16* fhW  = (_Float16*)(ws + 40697856);
    _Float16* flW  = (_Float16*)(ws + 71827456);
    u32*      ghistW  = (u32*)(ws + 109581056);
    u32*      gccntW  = (u32*)(ws + 109589248);
    u32*      gprefW  = (u32*)(ws + 109589280);
    u32*      gremW   = (u32*)(ws + 109589312);
    u32*      gdoneW  = (u32*)(ws + 109589344);
    u64*      arrW    = (u64*)(ws + 109597440);

    float* out0 = out;            // rpn_locs   (8,34200,4)
    float* out1 = out + 1094400;  // rpn_scores (8,34200,2)
    float* out2 = out + 1641600;  // rois       (2400,4)
    float* out3 = out + 1651200;  // anchors    (34200,4)

    // zero select control state (ghist + gccnt + gpref + grem + gdone)
    hipMemsetAsync(ws + 109581056, 0, 8416, stream);

    hipLaunchKernelGGL(k_split_wall, dim3(576), dim3(256), 0, stream,
                       w1, whW, wlW, lw, sw, wh2W, wl2W);
    for (int b = 0; b < 2; ++b) {
        hipLaunchKernelGGL(k_split_x, dim3(119, 16, 4), dim3(32, 8), 0, stream,
                           x + (size_t)b * 4 * CC * PP, xhW, xlW);
        hipLaunchKernelGGL(k_conv, dim3(480), dim3(256), 0, stream,
                           xhW, xlW, whW, wlW, b1, fhW, flW, b * 4);
    }
    hipLaunchKernelGGL(k_hgemm_post, dim3(60, NB), dim3(256), 0, stream,
                       fhW, flW, wh2W, wl2W, lb, sbias, imh, imw,
                       out0, out1, boxesW, scoresW, out3);
    for (int pass = 0; pass < 4; ++pass) {
        int sh = 24 - 8 * pass;
        hipLaunchKernelGGL(k_sel_histscan, dim3(8, NB), dim3(256), 0, stream,
                           scoresW, ghistW, gprefW, gremW, gdoneW, sh, pass);
    }
    hipLaunchKernelGGL(k_sel_collect, dim3(8, NB), dim3(256), 0, stream,
                       scoresW, gprefW, gccntW, arrW);
    hipLaunchKernelGGL(k_sel_sort2, dim3(2, NB), dim3(1024), 0, stream,
                       arrW, gccntW);
    hipLaunchKernelGGL(k_sel_merge, dim3((PRE + 1023) / 1024, NB), dim3(1024), 0, stream,
                       scoresW, (const float4*)boxesW, arrW,
                       sbW, (float4*)bbsW, areasW);
    hipLaunchKernelGGL(k_scan, dim3(NB), dim3(256), 0, stream,
                       sbW, (const float4*)bbsW, out2);
}